// Round 1
// baseline (795.688 us; speedup 1.0000x reference)
//
#include <hip/hip_runtime.h>
#include <cstdint>
#include <cstddef>

typedef unsigned short ushort_t;
typedef short s16x8 __attribute__((ext_vector_type(8)));
typedef float f32x4 __attribute__((ext_vector_type(4)));

#define MFMA(A,B,C) __builtin_amdgcn_mfma_f32_16x16x32_bf16((A),(B),(C),0,0,0)

__device__ __forceinline__ float b2f(ushort_t h){ return __uint_as_float(((unsigned)h)<<16); }
__device__ __forceinline__ ushort_t f2b(float f){
  unsigned u = __float_as_uint(f);
  u += 0x7FFFu + ((u >> 16) & 1u);
  return (ushort_t)(u >> 16);
}
// monotone float<->uint encoding for atomic min/max
__device__ __forceinline__ unsigned f2o(float f){
  unsigned u = __float_as_uint(f);
  return (u & 0x80000000u) ? ~u : (u | 0x80000000u);
}
__device__ __forceinline__ float o2f(unsigned u){
  unsigned b = (u & 0x80000000u) ? (u & 0x7FFFFFFFu) : ~u;
  return __uint_as_float(b);
}

struct QT { const float* w[10]; ushort_t* o[10]; int n[10]; };

__global__ void init_k(unsigned* slots){
  int t = threadIdx.x;
  if (t < 20) slots[t] = (t & 1) ? 0u : 0xFFFFFFFFu;
}

__global__ __launch_bounds__(256) void minmax_k(QT qt, unsigned* slots){
  int t = blockIdx.y;
  const float4* w = (const float4*)qt.w[t];
  int n4 = qt.n[t] >> 2;
  float mn = 3.4e38f, mx = -3.4e38f;
  for (int i = blockIdx.x*256 + threadIdx.x; i < n4; i += gridDim.x*256){
    float4 v = w[i];
    mn = fminf(mn, fminf(fminf(v.x, v.y), fminf(v.z, v.w)));
    mx = fmaxf(mx, fmaxf(fmaxf(v.x, v.y), fmaxf(v.z, v.w)));
  }
  #pragma unroll
  for (int o = 1; o < 64; o <<= 1){
    mn = fminf(mn, __shfl_xor(mn, o));
    mx = fmaxf(mx, __shfl_xor(mx, o));
  }
  __shared__ float smn[4], smx[4];
  int wv = threadIdx.x >> 6;
  if ((threadIdx.x & 63) == 0){ smn[wv] = mn; smx[wv] = mx; }
  __syncthreads();
  if (threadIdx.x == 0){
    mn = fminf(fminf(smn[0], smn[1]), fminf(smn[2], smn[3]));
    mx = fmaxf(fmaxf(smx[0], smx[1]), fmaxf(smx[2], smx[3]));
    atomicMin(&slots[2*t], f2o(mn));
    atomicMax(&slots[2*t+1], f2o(mx));
  }
}

__global__ __launch_bounds__(256) void dequant_k(QT qt, const unsigned* __restrict__ slots){
  int t = blockIdx.y;
  float mn = o2f(slots[2*t]), mx = o2f(slots[2*t+1]);
  float delta = (mx - mn) * (1.f/255.f);
  float zp = rintf(-mn / delta);
  const float4* w = (const float4*)qt.w[t];
  ushort4* o = (ushort4*)qt.o[t];
  int n4 = qt.n[t] >> 2;
  for (int i = blockIdx.x*256 + threadIdx.x; i < n4; i += gridDim.x*256){
    float4 v = w[i];
    ushort4 r;
    float q;
    q = fminf(fmaxf(rintf(v.x/delta) + zp, 0.f), 255.f); r.x = f2b((q - zp)*delta);
    q = fminf(fmaxf(rintf(v.y/delta) + zp, 0.f), 255.f); r.y = f2b((q - zp)*delta);
    q = fminf(fmaxf(rintf(v.z/delta) + zp, 0.f), 255.f); r.z = f2b((q - zp)*delta);
    q = fminf(fmaxf(rintf(v.w/delta) + zp, 0.f), 255.f); r.w = f2b((q - zp)*delta);
    o[i] = r;
  }
}

__global__ __launch_bounds__(256) void f2b_k(const float* __restrict__ in, ushort_t* __restrict__ out, int n4){
  for (int i = blockIdx.x*256 + threadIdx.x; i < n4; i += gridDim.x*256){
    float4 v = ((const float4*)in)[i];
    ushort4 r; r.x = f2b(v.x); r.y = f2b(v.y); r.z = f2b(v.z); r.w = f2b(v.w);
    ((ushort4*)out)[i] = r;
  }
}

// LayerNorm over rows of 1024 f32 -> bf16. One block per row.
__global__ __launch_bounds__(256) void ln_k(const float* __restrict__ x, const float* __restrict__ g,
                                            const float* __restrict__ b, ushort_t* __restrict__ out){
  int row = blockIdx.x, tid = threadIdx.x;
  float4 v = ((const float4*)(x + (size_t)row*1024))[tid];
  float s  = v.x + v.y + v.z + v.w;
  float s2 = v.x*v.x + v.y*v.y + v.z*v.z + v.w*v.w;
  #pragma unroll
  for (int o = 1; o < 64; o <<= 1){ s += __shfl_xor(s, o); s2 += __shfl_xor(s2, o); }
  __shared__ float rs[4], rs2[4];
  int wv = tid >> 6;
  if ((tid & 63) == 0){ rs[wv] = s; rs2[wv] = s2; }
  __syncthreads();
  s = rs[0]+rs[1]+rs[2]+rs[3]; s2 = rs2[0]+rs2[1]+rs2[2]+rs2[3];
  float mu = s * (1.f/1024.f);
  float var = s2 * (1.f/1024.f) - mu*mu;
  float rstd = rsqrtf(var + 1e-5f);
  float4 gv = ((const float4*)g)[tid], bv = ((const float4*)b)[tid];
  ushort4 r;
  r.x = f2b((v.x - mu)*rstd*gv.x + bv.x);
  r.y = f2b((v.y - mu)*rstd*gv.y + bv.y);
  r.z = f2b((v.z - mu)*rstd*gv.z + bv.z);
  r.w = f2b((v.w - mu)*rstd*gv.w + bv.w);
  ((ushort4*)(out + (size_t)row*1024))[tid] = r;
}

// C[M,N] = A[M,K] @ W[N,K]^T (+bias)(+resid). 128x128 tile, BK=64, 4 waves each 64x64.
__global__ __launch_bounds__(256) void gemm_k(
    const ushort_t* __restrict__ A, const ushort_t* __restrict__ W,
    const float* __restrict__ bias, const float* __restrict__ resid,
    float* __restrict__ outF, ushort_t* __restrict__ outB,
    int M, int N, int K)
{
  __shared__ ushort_t As[128*64];
  __shared__ ushort_t Bs[128*64];
  const int tid = threadIdx.x;
  const int lane = tid & 63, wv = tid >> 6;
  const int g = lane >> 4, qi = lane & 15;
  const int m0 = blockIdx.y * 128, n0 = blockIdx.x * 128;
  const int wr = (wv >> 1) * 64, wc = (wv & 1) * 64;
  f32x4 acc[4][4] = {};
  for (int kt = 0; kt < K; kt += 64){
    #pragma unroll
    for (int it = 0; it < 4; ++it){
      int s = it*256 + tid;
      int row = s >> 3, sl = s & 7;
      int gsl = sl ^ (row & 7);               // pre-swizzled global source (rule #21)
      int ar = m0 + row; ar = ar < M ? ar : M - 1;
      __builtin_amdgcn_global_load_lds(
        (const __attribute__((address_space(1))) void*)(A + (size_t)ar*K + kt + gsl*8),
        (__attribute__((address_space(3))) void*)(As + (size_t)(it*256 + wv*64)*8), 16, 0, 0);
      __builtin_amdgcn_global_load_lds(
        (const __attribute__((address_space(1))) void*)(W + (size_t)(n0 + row)*K + kt + gsl*8),
        (__attribute__((address_space(3))) void*)(Bs + (size_t)(it*256 + wv*64)*8), 16, 0, 0);
    }
    __syncthreads();
    #pragma unroll
    for (int kk = 0; kk < 2; ++kk){
      s16x8 af[4], bfr[4];
      #pragma unroll
      for (int mi = 0; mi < 4; ++mi){
        int row = wr + mi*16 + qi;
        int sl = (kk*4 + g) ^ (row & 7);      // swizzled read
        af[mi] = *(const s16x8*)(As + row*64 + sl*8);
      }
      #pragma unroll
      for (int ni = 0; ni < 4; ++ni){
        int row = wc + ni*16 + qi;
        int sl = (kk*4 + g) ^ (row & 7);
        bfr[ni] = *(const s16x8*)(Bs + row*64 + sl*8);
      }
      #pragma unroll
      for (int mi = 0; mi < 4; ++mi)
        #pragma unroll
        for (int ni = 0; ni < 4; ++ni)
          acc[mi][ni] = MFMA(af[mi], bfr[ni], acc[mi][ni]);
    }
    __syncthreads();
  }
  #pragma unroll
  for (int mi = 0; mi < 4; ++mi){
    #pragma unroll
    for (int r = 0; r < 4; ++r){
      int row = m0 + wr + mi*16 + g*4 + r;
      if (row >= M) continue;
      #pragma unroll
      for (int ni = 0; ni < 4; ++ni){
        int col = n0 + wc + ni*16 + qi;
        float v = acc[mi][ni][r];
        if (bias)  v += bias[col];
        if (resid) v += resid[(size_t)row*N + col];
        if (outF)  outF[(size_t)row*N + col] = v;
        else       outB[(size_t)row*N + col] = f2b(v);
      }
    }
  }
}

// Flash attention, H=16, DH=64. One wave = 16 q rows. Swapped QK^T; transposed PV.
__global__ __launch_bounds__(256) void attn_k(
    const ushort_t* __restrict__ Q, const ushort_t* __restrict__ Kp, const ushort_t* __restrict__ Vp,
    ushort_t* __restrict__ O, int nq, int nk, int qstride, int kvstride)
{
  const int tid = threadIdx.x, lane = tid & 63, wv = tid >> 6;
  const int g = lane >> 4, qi = lane & 15;
  const int b = blockIdx.y >> 4, h = blockIdx.y & 15;
  const int q0 = blockIdx.x*64 + wv*16;
  const ushort_t* Qr = Q + (size_t)(b*nq + q0 + qi)*qstride + h*64;
  s16x8 qf0 = *(const s16x8*)(Qr + g*8);
  s16x8 qf1 = *(const s16x8*)(Qr + 32 + g*8);
  const ushort_t* Kb = Kp + (size_t)b*nk*kvstride + h*64;
  const ushort_t* Vb = Vp + (size_t)b*nk*kvstride + h*64 + qi;
  f32x4 ot[4] = {};
  float m_run = -1e30f, l_run = 0.f;
  for (int kb = 0; kb < nk; kb += 32){
    f32x4 st0 = {}, st1 = {};
    {
      int kr = kb + qi; if (kr >= nk) kr = nk - 1;
      const ushort_t* kp = Kb + (size_t)kr*kvstride;
      st0 = MFMA(*(const s16x8*)(kp + g*8),      qf0, st0);
      st0 = MFMA(*(const s16x8*)(kp + 32 + g*8), qf1, st0);
      kr = kb + 16 + qi; if (kr >= nk) kr = nk - 1;
      kp = Kb + (size_t)kr*kvstride;
      st1 = MFMA(*(const s16x8*)(kp + g*8),      qf0, st1);
      st1 = MFMA(*(const s16x8*)(kp + 32 + g*8), qf1, st1);
    }
    float s[8];
    #pragma unroll
    for (int r = 0; r < 4; ++r){
      int k0 = kb + 4*g + r;
      int k1 = kb + 16 + 4*g + r;
      s[r]   = (k0 < nk) ? st0[r]*0.125f : -1e30f;
      s[4+r] = (k1 < nk) ? st1[r]*0.125f : -1e30f;
    }
    float bm = s[0];
    #pragma unroll
    for (int i = 1; i < 8; ++i) bm = fmaxf(bm, s[i]);
    bm = fmaxf(bm, __shfl_xor(bm, 16));
    bm = fmaxf(bm, __shfl_xor(bm, 32));
    float m_new = fmaxf(m_run, bm);
    float fac = __expf(m_run - m_new);
    float p[8], rsum = 0.f;
    #pragma unroll
    for (int i = 0; i < 8; ++i){ p[i] = __expf(s[i] - m_new); rsum += p[i]; }
    rsum += __shfl_xor(rsum, 16);
    rsum += __shfl_xor(rsum, 32);
    l_run = l_run * fac + rsum;
    m_run = m_new;
    #pragma unroll
    for (int dd = 0; dd < 4; ++dd)
      #pragma unroll
      for (int r = 0; r < 4; ++r) ot[dd][r] *= fac;
    // redistribute P into K=32 fragment layout: 8 packed shuffles
    unsigned pk[4];
    #pragma unroll
    for (int r = 0; r < 4; ++r)
      pk[r] = (unsigned)f2b(p[r]) | ((unsigned)f2b(p[4+r]) << 16);
    int srcbase = ((2*g) & 3) * 16 + qi;
    unsigned sh0[4], sh1[4];
    #pragma unroll
    for (int r = 0; r < 4; ++r){
      sh0[r] = (unsigned)__shfl((int)pk[r], srcbase);
      sh1[r] = (unsigned)__shfl((int)pk[r], srcbase + 16);
    }
    bool hi = (g >> 1) != 0;
    s16x8 pf;
    #pragma unroll
    for (int i = 0; i < 8; ++i){
      unsigned wval = (i < 4) ? sh0[i & 3] : sh1[i & 3];
      pf[i] = (short)(hi ? (wval >> 16) : (wval & 0xFFFFu));
    }
    // V fragments (V^T as A operand)
    s16x8 vf0, vf1, vf2, vf3;
    #pragma unroll
    for (int i = 0; i < 8; ++i){
      int kr = kb + 8*g + i; if (kr >= nk) kr = nk - 1;
      const ushort_t* vp = Vb + (size_t)kr*kvstride;
      vf0[i] = (short)vp[0];
      vf1[i] = (short)vp[16];
      vf2[i] = (short)vp[32];
      vf3[i] = (short)vp[48];
    }
    ot[0] = MFMA(vf0, pf, ot[0]);
    ot[1] = MFMA(vf1, pf, ot[1]);
    ot[2] = MFMA(vf2, pf, ot[2]);
    ot[3] = MFMA(vf3, pf, ot[3]);
  }
  float inv = 1.f / l_run;
  ushort_t* Or = O + (size_t)(b*nq + q0 + qi)*1024 + h*64;
  #pragma unroll
  for (int dd = 0; dd < 4; ++dd)
    #pragma unroll
    for (int r = 0; r < 4; ++r)
      Or[dd*16 + 4*g + r] = f2b(ot[dd][r] * inv);
}

__global__ __launch_bounds__(256) void geglu_k(const ushort_t* __restrict__ h, ushort_t* __restrict__ out){
  int idx = blockIdx.x*256 + threadIdx.x;   // 4096 rows * 512 groups of 8
  int r = idx >> 9, c = idx & 511;
  s16x8 hv = *(const s16x8*)(h + (size_t)r*8192 + c*8);
  s16x8 gv = *(const s16x8*)(h + (size_t)r*8192 + 4096 + c*8);
  s16x8 o;
  #pragma unroll
  for (int i = 0; i < 8; ++i){
    float gg = b2f((ushort_t)gv[i]);
    float t  = 0.7978845608f*(gg + 0.044715f*gg*gg*gg);
    float e  = __expf(2.f*t);
    float th = 1.f - 2.f/(e + 1.f);
    float ge = 0.5f*gg*(1.f + th);
    o[i] = (short)f2b(b2f((ushort_t)hv[i]) * ge);
  }
  *(s16x8*)(out + (size_t)r*4096 + c*8) = o;
}

extern "C" void kernel_launch(void* const* d_in, const int* in_sizes, int n_in,
                              void* d_out, int out_size, void* d_ws, size_t ws_size,
                              hipStream_t stream)
{
  const float* x    = (const float*)d_in[0];
  const float* ctx  = (const float*)d_in[1];
  const float* ln1g = (const float*)d_in[2];
  const float* ln1b = (const float*)d_in[3];
  const float* ln2g = (const float*)d_in[4];
  const float* ln2b = (const float*)d_in[5];
  const float* ln3g = (const float*)d_in[6];
  const float* ln3b = (const float*)d_in[7];
  const float* q1w  = (const float*)d_in[8];
  const float* k1w  = (const float*)d_in[9];
  const float* v1w  = (const float*)d_in[10];
  const float* o1w  = (const float*)d_in[11];
  const float* o1b  = (const float*)d_in[12];
  const float* q2w  = (const float*)d_in[13];
  const float* k2w  = (const float*)d_in[14];
  const float* v2w  = (const float*)d_in[15];
  const float* o2w  = (const float*)d_in[16];
  const float* o2b  = (const float*)d_in[17];
  const float* ff1w = (const float*)d_in[18];
  const float* ff1b = (const float*)d_in[19];
  const float* ff2w = (const float*)d_in[20];
  const float* ff2b = (const float*)d_in[21];

  char* base = (char*)d_ws;
  size_t off = 0;
  auto alloc = [&](size_t bytes) -> char* {
    char* p = base + off;
    off += (bytes + 255) & ~(size_t)255;
    return p;
  };
  unsigned*  slots = (unsigned*)alloc(80);
  ushort_t*  ctxb  = (ushort_t*)alloc((size_t)154*768*2);
  ushort_t*  wqkv1 = (ushort_t*)alloc((size_t)3072*1024*2);
  ushort_t*  o1d   = (ushort_t*)alloc((size_t)1024*1024*2);
  ushort_t*  q2d   = (ushort_t*)alloc((size_t)1024*1024*2);
  ushort_t*  wkv2  = (ushort_t*)alloc((size_t)2048*768*2);
  ushort_t*  o2d   = (ushort_t*)alloc((size_t)1024*1024*2);
  ushort_t*  f1d   = (ushort_t*)alloc((size_t)8192*1024*2);
  ushort_t*  f2d   = (ushort_t*)alloc((size_t)1024*4096*2);
  ushort_t*  lnb   = (ushort_t*)alloc((size_t)4096*1024*2);
  ushort_t*  qkvb  = (ushort_t*)alloc((size_t)4096*3072*2);  // + q2b below = contiguous 32MB, reused as actb
  ushort_t*  q2b   = (ushort_t*)alloc((size_t)4096*1024*2);
  ushort_t*  atb   = (ushort_t*)alloc((size_t)4096*1024*2);
  ushort_t*  kvb   = (ushort_t*)alloc((size_t)154*2048*2);
  float*     x1    = (float*)alloc((size_t)4096*1024*4);
  float*     x2    = (float*)alloc((size_t)4096*1024*4);
  ushort_t*  hb    = (ushort_t*)alloc((size_t)4096*8192*2);
  ushort_t*  actb  = qkvb;  // [4096,4096] overlays qkvb+q2b (both dead by GEGLU time)

  QT qt;
  qt.w[0]=q1w;  qt.o[0]=wqkv1;               qt.n[0]=1024*1024;
  qt.w[1]=k1w;  qt.o[1]=wqkv1+1024*1024;     qt.n[1]=1024*1024;
  qt.w[2]=v1w;  qt.o[2]=wqkv1+2*1024*1024;   qt.n[2]=1024*1024;
  qt.w[3]=o1w;  qt.o[3]=o1d;                 qt.n[3]=1024*1024;
  qt.w[4]=q2w;  qt.o[4]=q2d;                 qt.n[4]=1024*1024;
  qt.w[5]=k2w;  qt.o[5]=wkv2;                qt.n[5]=1024*768;
  qt.w[6]=v2w;  qt.o[6]=wkv2+1024*768;       qt.n[6]=1024*768;
  qt.w[7]=o2w;  qt.o[7]=o2d;                 qt.n[7]=1024*1024;
  qt.w[8]=ff1w; qt.o[8]=f1d;                 qt.n[8]=8192*1024;
  qt.w[9]=ff2w; qt.o[9]=f2d;                 qt.n[9]=1024*4096;

  init_k<<<1, 64, 0, stream>>>(slots);
  minmax_k<<<dim3(64,10), 256, 0, stream>>>(qt, slots);
  dequant_k<<<dim3(64,10), 256, 0, stream>>>(qt, slots);
  f2b_k<<<64, 256, 0, stream>>>(ctx, ctxb, 154*768/4);

  // --- block 1: self attention ---
  ln_k<<<4096, 256, 0, stream>>>(x, ln1g, ln1b, lnb);
  gemm_k<<<dim3(24, 32), 256, 0, stream>>>(lnb, wqkv1, nullptr, nullptr,
                                           nullptr, qkvb, 4096, 3072, 1024);
  attn_k<<<dim3(32, 32), 256, 0, stream>>>(qkvb, qkvb+1024, qkvb+2048, atb,
                                           2048, 2048, 3072, 3072);
  gemm_k<<<dim3(8, 32), 256, 0, stream>>>(atb, o1d, o1b, x, x1, nullptr, 4096, 1024, 1024);

  // --- block 2: cross attention ---
  ln_k<<<4096, 256, 0, stream>>>(x1, ln2g, ln2b, lnb);
  gemm_k<<<dim3(8, 32), 256, 0, stream>>>(lnb, q2d, nullptr, nullptr,
                                          nullptr, q2b, 4096, 1024, 1024);
  gemm_k<<<dim3(16, 2), 256, 0, stream>>>(ctxb, wkv2, nullptr, nullptr,
                                          nullptr, kvb, 154, 2048, 768);
  attn_k<<<dim3(32, 32), 256, 0, stream>>>(q2b, kvb, kvb+1024, atb,
                                           2048, 77, 1024, 2048);
  gemm_k<<<dim3(8, 32), 256, 0, stream>>>(atb, o2d, o2b, x1, x2, nullptr, 4096, 1024, 1024);

  // --- block 3: GEGLU FF ---
  ln_k<<<4096, 256, 0, stream>>>(x2, ln3g, ln3b, lnb);
  gemm_k<<<dim3(64, 32), 256, 0, stream>>>(lnb, f1d, ff1b, nullptr,
                                           nullptr, hb, 4096, 8192, 1024);
  geglu_k<<<8192, 256, 0, stream>>>(hb, actb);
  gemm_k<<<dim3(8, 32), 256, 0, stream>>>(actb, f2d, ff2b, x2,
                                          (float*)d_out, nullptr, 4096, 1024, 4096);
}